// Round 1
// baseline (4390.454 us; speedup 1.0000x reference)
//
#include <hip/hip_runtime.h>
#include <math.h>

#define NB 2
#define SS 3072
#define CC 1536
#define NH 12
#define DH 128
#define NTOK (NB * SS)

// ---------------------------------------------------------------------------
// Y = X @ W^T + bias.  X: (M=6144, K=1536) row-major, W: (N=1536, K) row-major.
// head_major=1: write Y[tok][j] to (B, NH, S, DH) layout; else plain (M, N).
// 64x64 tile, 256 threads (16x16), 4x4 microtile, K-chunks of 16.
// ---------------------------------------------------------------------------
__global__ __launch_bounds__(256) void gemm_xwt(
    const float* __restrict__ X, const float* __restrict__ Wt,
    const float* __restrict__ bias, float* __restrict__ Y, int head_major)
{
    __shared__ float Xs[16][68];   // [kk][row], pad 68 (float4-aligned)
    __shared__ float Ws[16][68];
    const int tid = threadIdx.x;
    const int i0 = blockIdx.x * 64;
    const int j0 = blockIdx.y * 64;
    const int tx = tid & 15, ty = tid >> 4;
    const int lkk = tid & 15, lrow = tid >> 4;
    float acc[4][4] = {};

    for (int k0 = 0; k0 < CC; k0 += 16) {
        #pragma unroll
        for (int it = 0; it < 4; ++it) {
            int row = lrow + it * 16;
            Xs[lkk][row] = X[(size_t)(i0 + row) * CC + k0 + lkk];
            Ws[lkk][row] = Wt[(size_t)(j0 + row) * CC + k0 + lkk];
        }
        __syncthreads();
        #pragma unroll
        for (int kk = 0; kk < 16; ++kk) {
            float4 a = *(const float4*)&Xs[kk][ty * 4];
            float4 b = *(const float4*)&Ws[kk][tx * 4];
            float av[4] = {a.x, a.y, a.z, a.w};
            float bv[4] = {b.x, b.y, b.z, b.w};
            #pragma unroll
            for (int i = 0; i < 4; ++i)
                #pragma unroll
                for (int j = 0; j < 4; ++j)
                    acc[i][j] = fmaf(av[i], bv[j], acc[i][j]);
        }
        __syncthreads();
    }

    const int jb = j0 + tx * 4;
    #pragma unroll
    for (int ri = 0; ri < 4; ++ri) {
        int i = i0 + ty * 4 + ri;
        float4 r;
        r.x = acc[ri][0] + bias[jb + 0];
        r.y = acc[ri][1] + bias[jb + 1];
        r.z = acc[ri][2] + bias[jb + 2];
        r.w = acc[ri][3] + bias[jb + 3];
        if (head_major) {
            int b = i / SS, s = i - b * SS;
            int h = jb >> 7, td = jb & 127;   // 4-wide chunk never crosses a head
            *(float4*)&Y[((size_t)(b * NH + h) * SS + s) * DH + td] = r;
        } else {
            *(float4*)&Y[(size_t)i * CC + jb] = r;
        }
    }
}

// ---------------------------------------------------------------------------
// In-place RMSNorm (over full C per token) + RoPE on a (B, NH, S, DH) tensor.
// One block (256 threads) per token; 768 pairs -> 3 pairs/thread.
// ---------------------------------------------------------------------------
__global__ __launch_bounds__(256) void norm_rope(
    float* __restrict__ t, const float* __restrict__ w,
    const float* __restrict__ freqs, const int* __restrict__ gsz)
{
    const int tok = blockIdx.x;
    const int b = tok / SS, s = tok - b * SS;
    const int Hg = gsz[1], Wg = gsz[2];
    const int f  = s / (Hg * Wg);
    const int rem = s - f * Hg * Wg;
    const int hh = rem / Wg;
    const int ww = rem - hh * Wg;
    const int tid = threadIdx.x;

    float2 vals[3];
    size_t addrs[3];
    float ss = 0.f;
    #pragma unroll
    for (int kt = 0; kt < 3; ++kt) {
        int p = tid + kt * 256;            // pair index 0..767
        int h = p >> 6, pj = p & 63;
        size_t addr = ((size_t)(b * NH + h) * SS + s) * DH + 2 * pj;
        addrs[kt] = addr;
        float2 v = *(const float2*)&t[addr];
        vals[kt] = v;
        ss += v.x * v.x + v.y * v.y;
    }
    #pragma unroll
    for (int off = 32; off > 0; off >>= 1) ss += __shfl_down(ss, off, 64);
    __shared__ float red[4];
    if ((tid & 63) == 0) red[tid >> 6] = ss;
    __syncthreads();
    const float total = red[0] + red[1] + red[2] + red[3];
    const float rstd = rsqrtf(total * (1.0f / CC) + 1e-6f);

    #pragma unroll
    for (int kt = 0; kt < 3; ++kt) {
        int p = tid + kt * 256;
        int h = p >> 6, pj = p & 63;
        int row = (pj < 22) ? f : ((pj < 43) ? hh : ww);
        float ang = freqs[row * 64 + pj];
        float sn, cs;
        sincosf(ang, &sn, &cs);
        int ch = h * DH + 2 * pj;
        float te = vals[kt].x * rstd * w[ch];
        float to = vals[kt].y * rstd * w[ch + 1];
        float2 o;
        o.x = te * cs - to * sn;
        o.y = te * sn + to * cs;
        *(float2*)&t[addrs[kt]] = o;
    }
}

// ---------------------------------------------------------------------------
// Flash attention, fp32. Q/K/V in (B, NH, S, DH). One block per (b, h, qtile64).
// Online softmax; key tiles truncated at ceil(seq_len/64); -inf masking.
// Output written to (B, S, C).
// ---------------------------------------------------------------------------
__global__ __launch_bounds__(256) void flash_attn(
    const float* __restrict__ q, const float* __restrict__ k,
    const float* __restrict__ v, const int* __restrict__ seq_lens,
    float* __restrict__ out)
{
    __shared__ float Qs[64][132];
    __shared__ float Ks[64][132];
    __shared__ float Vs[64][132];
    __shared__ float Ps[64][65];
    __shared__ float mrow[64], lrow[64], arow[64];

    const int bid = blockIdx.x;
    const int qt = bid % 48;
    const int h  = (bid / 48) % NH;
    const int b  = bid / (48 * NH);
    const int slen = seq_lens[b];
    const int s0 = qt * 64;
    const float scale = 0.088388347648318447f;  // 1/sqrt(128)

    const float* qbase = q + ((size_t)(b * NH + h) * SS + s0) * DH;
    const float* kbase = k + ((size_t)(b * NH + h) * SS) * DH;
    const float* vbase = v + ((size_t)(b * NH + h) * SS) * DH;
    const int tid = threadIdx.x;
    const int tx = tid & 15, ty = tid >> 4;

    #pragma unroll
    for (int it = 0; it < 8; ++it) {
        int id = it * 256 + tid;
        int row = id >> 5, c4 = (id & 31) * 4;
        float4 vv = *(const float4*)&qbase[row * DH + c4];
        vv.x *= scale; vv.y *= scale; vv.z *= scale; vv.w *= scale;
        *(float4*)&Qs[row][c4] = vv;
    }
    if (tid < 64) { mrow[tid] = -INFINITY; lrow[tid] = 0.f; }

    float acc[4][8] = {};
    const int ntiles = (slen + 63) >> 6;

    for (int kt = 0; kt < ntiles; ++kt) {
        __syncthreads();   // protect Ks/Vs/Ps from previous iteration's readers
        #pragma unroll
        for (int it = 0; it < 8; ++it) {
            int id = it * 256 + tid;
            int row = id >> 5, c4 = (id & 31) * 4;
            *(float4*)&Ks[row][c4] = *(const float4*)&kbase[(size_t)(kt * 64 + row) * DH + c4];
            *(float4*)&Vs[row][c4] = *(const float4*)&vbase[(size_t)(kt * 64 + row) * DH + c4];
        }
        __syncthreads();

        // scores: 4x4 per thread over d=128
        float sc[4][4] = {};
        #pragma unroll 2
        for (int t = 0; t < DH; t += 4) {
            float4 aa[4], bb[4];
            #pragma unroll
            for (int i = 0; i < 4; ++i) aa[i] = *(const float4*)&Qs[ty * 4 + i][t];
            #pragma unroll
            for (int j = 0; j < 4; ++j) bb[j] = *(const float4*)&Ks[tx * 4 + j][t];
            #pragma unroll
            for (int i = 0; i < 4; ++i)
                #pragma unroll
                for (int j = 0; j < 4; ++j) {
                    sc[i][j] = fmaf(aa[i].x, bb[j].x, sc[i][j]);
                    sc[i][j] = fmaf(aa[i].y, bb[j].y, sc[i][j]);
                    sc[i][j] = fmaf(aa[i].z, bb[j].z, sc[i][j]);
                    sc[i][j] = fmaf(aa[i].w, bb[j].w, sc[i][j]);
                }
        }
        #pragma unroll
        for (int i = 0; i < 4; ++i)
            #pragma unroll
            for (int j = 0; j < 4; ++j) {
                int kidx = kt * 64 + tx * 4 + j;
                Ps[ty * 4 + i][tx * 4 + j] = (kidx < slen) ? sc[i][j] : -INFINITY;
            }
        __syncthreads();

        // online softmax per row (64 threads, one row each)
        if (tid < 64) {
            int r = tid;
            float mprev = mrow[r];
            float mx = mprev;
            for (int j = 0; j < 64; ++j) mx = fmaxf(mx, Ps[r][j]);
            float alpha = __expf(mprev - mx);   // first tile: exp(-inf)=0
            float lsum = 0.f;
            for (int j = 0; j < 64; ++j) {
                float p = __expf(Ps[r][j] - mx);
                Ps[r][j] = p;
                lsum += p;
            }
            mrow[r] = mx;
            lrow[r] = lrow[r] * alpha + lsum;
            arow[r] = alpha;
        }
        __syncthreads();

        // O = O*alpha + P @ V   (4 rows x 8 cols per thread)
        #pragma unroll
        for (int i = 0; i < 4; ++i) {
            float al = arow[ty * 4 + i];
            #pragma unroll
            for (int c = 0; c < 8; ++c) acc[i][c] *= al;
        }
        #pragma unroll 4
        for (int j = 0; j < 64; ++j) {
            float4 v0 = *(const float4*)&Vs[j][tx * 8];
            float4 v1 = *(const float4*)&Vs[j][tx * 8 + 4];
            #pragma unroll
            for (int i = 0; i < 4; ++i) {
                float p = Ps[ty * 4 + i][j];
                acc[i][0] = fmaf(p, v0.x, acc[i][0]);
                acc[i][1] = fmaf(p, v0.y, acc[i][1]);
                acc[i][2] = fmaf(p, v0.z, acc[i][2]);
                acc[i][3] = fmaf(p, v0.w, acc[i][3]);
                acc[i][4] = fmaf(p, v1.x, acc[i][4]);
                acc[i][5] = fmaf(p, v1.y, acc[i][5]);
                acc[i][6] = fmaf(p, v1.z, acc[i][6]);
                acc[i][7] = fmaf(p, v1.w, acc[i][7]);
            }
        }
    }

    #pragma unroll
    for (int i = 0; i < 4; ++i) {
        int r = ty * 4 + i;
        float inv = 1.0f / lrow[r];
        size_t base = ((size_t)b * SS + s0 + r) * CC + h * DH + tx * 8;
        float4 o0, o1;
        o0.x = acc[i][0] * inv; o0.y = acc[i][1] * inv;
        o0.z = acc[i][2] * inv; o0.w = acc[i][3] * inv;
        o1.x = acc[i][4] * inv; o1.y = acc[i][5] * inv;
        o1.z = acc[i][6] * inv; o1.w = acc[i][7] * inv;
        *(float4*)&out[base] = o0;
        *(float4*)&out[base + 4] = o1;
    }
}

// ---------------------------------------------------------------------------
extern "C" void kernel_launch(void* const* d_in, const int* in_sizes, int n_in,
                              void* d_out, int out_size, void* d_ws, size_t ws_size,
                              hipStream_t stream) {
    const float* x         = (const float*)d_in[0];
    const int*   seq_lens  = (const int*)d_in[1];
    const int*   grid_sizes= (const int*)d_in[2];
    const float* freqs     = (const float*)d_in[3];
    const float* Wq        = (const float*)d_in[4];
    const float* bq        = (const float*)d_in[5];
    const float* Wk        = (const float*)d_in[6];
    const float* bk        = (const float*)d_in[7];
    const float* Wv        = (const float*)d_in[8];
    const float* bv        = (const float*)d_in[9];
    const float* Wo        = (const float*)d_in[10];
    const float* bo        = (const float*)d_in[11];
    const float* nqw       = (const float*)d_in[12];
    const float* nkw       = (const float*)d_in[13];
    float* out = (float*)d_out;

    const size_t tensor_elems = (size_t)NB * SS * CC;  // 9,437,184 floats
    float* qb = (float*)d_ws;
    float* kb = qb + tensor_elems;
    float* vb = kb + tensor_elems;
    float* ab = vb + tensor_elems;

    dim3 gg(NTOK / 64, CC / 64), gb(256);
    gemm_xwt<<<gg, gb, 0, stream>>>(x, Wq, bq, qb, 1);
    gemm_xwt<<<gg, gb, 0, stream>>>(x, Wk, bk, kb, 1);
    gemm_xwt<<<gg, gb, 0, stream>>>(x, Wv, bv, vb, 1);
    norm_rope<<<dim3(NTOK), 256, 0, stream>>>(qb, nqw, freqs, grid_sizes);
    norm_rope<<<dim3(NTOK), 256, 0, stream>>>(kb, nkw, freqs, grid_sizes);
    flash_attn<<<dim3(NB * NH * (SS / 64)), 256, 0, stream>>>(qb, kb, vb, seq_lens, ab);
    gemm_xwt<<<gg, gb, 0, stream>>>(ab, Wo, bo, out, 0);
}

// Round 2
// 688.609 us; speedup vs baseline: 6.3758x; 6.3758x over previous
//
#include <hip/hip_runtime.h>
#include <math.h>

#define NB 2
#define SS 3072
#define CC 1536
#define NH 12
#define DH 128
#define NTOK (NB * SS)
#define LOG2E 1.4426950408889634f

typedef __attribute__((ext_vector_type(8))) short short8;
typedef __attribute__((ext_vector_type(4))) float floatx4;

#define GLOAD(g, l) __builtin_amdgcn_global_load_lds( \
    (const __attribute__((address_space(1))) void*)(g), \
    (__attribute__((address_space(3))) void*)(l), 16, 0, 0)

__device__ __forceinline__ unsigned short f2bf(float f) {
    unsigned u = __float_as_uint(f);
    u += 0x7fffu + ((u >> 16) & 1u);   // RNE
    return (unsigned short)(u >> 16);
}
__device__ __forceinline__ float bf2f(unsigned short h) {
    return __uint_as_float(((unsigned)h) << 16);
}

// ---------------------------------------------------------------------------
// fp32 -> bf16 cast, 4 elems/thread. n divisible by 1024.
// ---------------------------------------------------------------------------
__global__ __launch_bounds__(256) void cast_bf16(
    const float* __restrict__ in, unsigned short* __restrict__ o, int n)
{
    int i = (blockIdx.x * 256 + threadIdx.x) * 4;
    if (i >= n) return;
    float4 v = *(const float4*)&in[i];
    uint2 u;
    u.x = (unsigned)f2bf(v.x) | ((unsigned)f2bf(v.y) << 16);
    u.y = (unsigned)f2bf(v.z) | ((unsigned)f2bf(v.w) << 16);
    *(uint2*)&o[i] = u;
}

// ---------------------------------------------------------------------------
// MFMA GEMM: C(6144,1536) = X(6144,1536) @ W(1536,1536)^T + bias
// X, W bf16 row-major. 128x128 tile, BK=32, 256 threads (4 waves), each wave
// a 64x64 quadrant via 4x4 grid of 16x16x32 MFMAs.
// MODE 0: fp32 row-major out. MODE 2: bf16 (B,NH,DH,S). MODE 3: bf16 (B,NH,S,DH).
// ---------------------------------------------------------------------------
template<int MODE>
__global__ __launch_bounds__(256) void gemm_mfma(
    const unsigned short* __restrict__ X, const unsigned short* __restrict__ Wt,
    const float* __restrict__ bias, void* __restrict__ Y)
{
    __shared__ unsigned short As[128 * 32];
    __shared__ unsigned short Bs[128 * 32];
    const int tid = threadIdx.x;
    const int w = tid >> 6, l = tid & 63;
    const int i0 = blockIdx.x * 128, j0 = blockIdx.y * 128;
    const int srow = tid >> 2;            // 0..63
    const int sk8 = (tid & 3) * 8;        // bf16 col offset of 16B chunk

    floatx4 acc[4][4] = {};

    for (int k0 = 0; k0 < CC; k0 += 32) {
        __syncthreads();
        GLOAD(X + (size_t)(i0 + srow) * CC + k0 + sk8,       As + (size_t)tid * 8);
        GLOAD(X + (size_t)(i0 + 64 + srow) * CC + k0 + sk8,  As + (size_t)(256 + tid) * 8);
        GLOAD(Wt + (size_t)(j0 + srow) * CC + k0 + sk8,      Bs + (size_t)tid * 8);
        GLOAD(Wt + (size_t)(j0 + 64 + srow) * CC + k0 + sk8, Bs + (size_t)(256 + tid) * 8);
        __syncthreads();

        const int wr = (w >> 1) * 64, wc = (w & 1) * 64;
        short8 af[4], bf[4];
        #pragma unroll
        for (int mb = 0; mb < 4; ++mb)
            af[mb] = *(const short8*)&As[(wr + mb * 16 + (l & 15)) * 32 + (l >> 4) * 8];
        #pragma unroll
        for (int nb = 0; nb < 4; ++nb)
            bf[nb] = *(const short8*)&Bs[(wc + nb * 16 + (l & 15)) * 32 + (l >> 4) * 8];
        #pragma unroll
        for (int mb = 0; mb < 4; ++mb)
            #pragma unroll
            for (int nb = 0; nb < 4; ++nb)
                acc[mb][nb] = __builtin_amdgcn_mfma_f32_16x16x32_bf16(
                    af[mb], bf[nb], acc[mb][nb], 0, 0, 0);
    }

    const int wr = (w >> 1) * 64, wc = (w & 1) * 64;
    #pragma unroll
    for (int mb = 0; mb < 4; ++mb) {
        #pragma unroll
        for (int nb = 0; nb < 4; ++nb) {
            const int n = j0 + wc + nb * 16 + (l & 15);
            const float bv = bias[n];
            #pragma unroll
            for (int r = 0; r < 4; ++r) {
                const int m = i0 + wr + mb * 16 + (l >> 4) * 4 + r;
                float val = acc[mb][nb][r] + bv;
                if (MODE == 0) {
                    ((float*)Y)[(size_t)m * CC + n] = val;
                } else {
                    const int b = (m >= SS) ? 1 : 0;
                    const int s = m - b * SS;
                    const int h = n >> 7, td = n & 127;
                    if (MODE == 3)
                        ((unsigned short*)Y)[((size_t)(b * NH + h) * SS + s) * DH + td] = f2bf(val);
                    else  // MODE 2: transposed (B,NH,DH,S)
                        ((unsigned short*)Y)[((size_t)(b * NH + h) * DH + td) * SS + s] = f2bf(val);
                }
            }
        }
    }
}

// ---------------------------------------------------------------------------
// In-place RMSNorm (full C per token) + RoPE on bf16 (B,NH,S,DH).
// outscale folds attention 1/sqrt(d) into q.
// ---------------------------------------------------------------------------
__global__ __launch_bounds__(256) void norm_rope(
    unsigned short* __restrict__ t, const float* __restrict__ wgt,
    const float* __restrict__ freqs, const int* __restrict__ gsz, float outscale)
{
    const int tok = blockIdx.x;
    const int b = tok / SS, s = tok - b * SS;
    const int Hg = gsz[1], Wg = gsz[2];
    const int f = s / (Hg * Wg);
    const int rem = s - f * Hg * Wg;
    const int hh = rem / Wg;
    const int ww = rem - hh * Wg;
    const int tid = threadIdx.x;

    float2 vals[3];
    size_t addrs[3];
    float ss = 0.f;
    #pragma unroll
    for (int kt = 0; kt < 3; ++kt) {
        int p = tid + kt * 256;                 // pair 0..767
        int h = p >> 6, pj = p & 63;
        size_t addr = ((size_t)(b * NH + h) * SS + s) * DH + 2 * pj;
        addrs[kt] = addr;
        unsigned u = *(const unsigned*)&t[addr];
        float2 v;
        v.x = __uint_as_float(u << 16);
        v.y = __uint_as_float(u & 0xffff0000u);
        vals[kt] = v;
        ss += v.x * v.x + v.y * v.y;
    }
    #pragma unroll
    for (int off = 32; off > 0; off >>= 1) ss += __shfl_down(ss, off, 64);
    __shared__ float red[4];
    if ((tid & 63) == 0) red[tid >> 6] = ss;
    __syncthreads();
    const float total = red[0] + red[1] + red[2] + red[3];
    const float rstd = rsqrtf(total * (1.0f / CC) + 1e-6f) * outscale;

    #pragma unroll
    for (int kt = 0; kt < 3; ++kt) {
        int p = tid + kt * 256;
        int h = p >> 6, pj = p & 63;
        int row = (pj < 22) ? f : ((pj < 43) ? hh : ww);
        float ang = freqs[row * 64 + pj];
        float sn, cs;
        sincosf(ang, &sn, &cs);
        int ch = h * DH + 2 * pj;
        float te = vals[kt].x * rstd * wgt[ch];
        float to = vals[kt].y * rstd * wgt[ch + 1];
        unsigned o = (unsigned)f2bf(te * cs - to * sn) |
                     ((unsigned)f2bf(te * sn + to * cs) << 16);
        *(unsigned*)&t[addrs[kt]] = o;
    }
}

// ---------------------------------------------------------------------------
// MFMA flash attention. q,k: (B,NH,S,DH) bf16 (q pre-scaled). vt: (B,NH,DH,S)
// bf16. out: (B,S,C) bf16. One block = (b,h,64-row q-tile), 4 waves; wave w
// owns q-rows [16w,16w+16). Online softmax in MFMA C-layout.
// ---------------------------------------------------------------------------
__global__ __launch_bounds__(256) void flash_attn_mfma(
    const unsigned short* __restrict__ qg, const unsigned short* __restrict__ kg,
    const unsigned short* __restrict__ vg, const int* __restrict__ seq_lens,
    unsigned short* __restrict__ out)
{
    __shared__ unsigned short Qs[4 * 64 * 32];   // [kc][qrow][k32]
    __shared__ unsigned short Ks[4 * 64 * 32];   // [kc][key][k32]
    __shared__ unsigned short Vs[2 * 128 * 32];  // [ks][dcol][key32]
    __shared__ unsigned short Ps[4][16 * 72];    // per wave [qrow][key], pad 72

    const int tid = threadIdx.x;
    const int w = tid >> 6, l = tid & 63;
    const int bid = blockIdx.x;
    const int qt = bid % 48;
    const int h = (bid / 48) % NH;
    const int b = bid / (48 * NH);
    const int slen = seq_lens[b];
    const int s0 = qt * 64;

    const unsigned short* qbase = qg + ((size_t)(b * NH + h) * SS + s0) * DH;
    const unsigned short* kbase = kg + ((size_t)(b * NH + h) * SS) * DH;
    const unsigned short* vbase = vg + ((size_t)(b * NH + h) * DH) * SS;

    // stage Q: 1024 16B chunks; LDS layout [kc][row][32]
    #pragma unroll
    for (int i = 0; i < 4; ++i) {
        int cid = i * 256 + tid;
        int kc = cid >> 8, rem = cid & 255, row = rem >> 2, k8 = (rem & 3) * 8;
        GLOAD(qbase + row * DH + kc * 32 + k8, Qs + (size_t)cid * 8);
    }
    __syncthreads();
    short8 qf[4];
    #pragma unroll
    for (int kc = 0; kc < 4; ++kc)
        qf[kc] = *(const short8*)&Qs[kc * 2048 + (w * 16 + (l & 15)) * 32 + (l >> 4) * 8];

    floatx4 acc[8] = {};
    float mrow[4] = {-1e30f, -1e30f, -1e30f, -1e30f};
    float lrow[4] = {};
    const int ntiles = (slen + 63) >> 6;

    for (int kt = 0; kt < ntiles; ++kt) {
        __syncthreads();    // previous iteration's Ks/Vs readers done
        #pragma unroll
        for (int i = 0; i < 4; ++i) {
            int cid = i * 256 + tid;
            int kc = cid >> 8, rem = cid & 255, row = rem >> 2, k8 = (rem & 3) * 8;
            GLOAD(kbase + (size_t)(kt * 64 + row) * DH + kc * 32 + k8, Ks + (size_t)cid * 8);
        }
        #pragma unroll
        for (int i = 0; i < 4; ++i) {
            int cid = i * 256 + tid;
            int ks = cid >> 9, rem = cid & 511, dc = rem >> 2, k8 = (rem & 3) * 8;
            GLOAD(vbase + (size_t)dc * SS + kt * 64 + ks * 32 + k8, Vs + (size_t)cid * 8);
        }
        __syncthreads();

        // S = Q K^T (per wave: 16 q-rows x 64 keys)
        floatx4 sv[4] = {};
        #pragma unroll
        for (int nb = 0; nb < 4; ++nb)
            #pragma unroll
            for (int kc = 0; kc < 4; ++kc) {
                short8 kf = *(const short8*)&Ks[kc * 2048 + (nb * 16 + (l & 15)) * 32 + (l >> 4) * 8];
                sv[nb] = __builtin_amdgcn_mfma_f32_16x16x32_bf16(qf[kc], kf, sv[nb], 0, 0, 0);
            }

        // mask + online softmax (C layout: col=l&15, row=(l>>4)*4+r)
        float vals[4][4];
        #pragma unroll
        for (int nb = 0; nb < 4; ++nb) {
            const int key = kt * 64 + nb * 16 + (l & 15);
            #pragma unroll
            for (int r = 0; r < 4; ++r)
                vals[nb][r] = (key < slen) ? sv[nb][r] : -1e30f;
        }
        float alpha[4];
        #pragma unroll
        for (int r = 0; r < 4; ++r) {
            float tm = fmaxf(fmaxf(vals[0][r], vals[1][r]), fmaxf(vals[2][r], vals[3][r]));
            #pragma unroll
            for (int mm = 1; mm < 16; mm <<= 1) tm = fmaxf(tm, __shfl_xor(tm, mm, 64));
            float mn = fmaxf(mrow[r], tm);
            alpha[r] = exp2f((mrow[r] - mn) * LOG2E);
            mrow[r] = mn;
        }
        #pragma unroll
        for (int r = 0; r < 4; ++r) {
            float lsum = 0.f;
            #pragma unroll
            for (int nb = 0; nb < 4; ++nb) {
                float p = exp2f((vals[nb][r] - mrow[r]) * LOG2E);
                vals[nb][r] = p;
                lsum += p;
            }
            #pragma unroll
            for (int mm = 1; mm < 16; mm <<= 1) lsum += __shfl_xor(lsum, mm, 64);
            lrow[r] = lrow[r] * alpha[r] + lsum;
        }
        // write P (bf16) to this wave's LDS slab
        #pragma unroll
        for (int nb = 0; nb < 4; ++nb)
            #pragma unroll
            for (int r = 0; r < 4; ++r)
                Ps[w][((l >> 4) * 4 + r) * 72 + nb * 16 + (l & 15)] = f2bf(vals[nb][r]);

        // rescale O
        #pragma unroll
        for (int nb2 = 0; nb2 < 8; ++nb2)
            #pragma unroll
            for (int r = 0; r < 4; ++r)
                acc[nb2][r] *= alpha[r];

        // O += P V
        short8 pa[2];
        #pragma unroll
        for (int ks = 0; ks < 2; ++ks)
            pa[ks] = *(const short8*)&Ps[w][(l & 15) * 72 + ks * 32 + (l >> 4) * 8];
        #pragma unroll
        for (int nb2 = 0; nb2 < 8; ++nb2)
            #pragma unroll
            for (int ks = 0; ks < 2; ++ks) {
                short8 vf = *(const short8*)&Vs[ks * 4096 + (nb2 * 16 + (l & 15)) * 32 + (l >> 4) * 8];
                acc[nb2] = __builtin_amdgcn_mfma_f32_16x16x32_bf16(pa[ks], vf, acc[nb2], 0, 0, 0);
            }
    }

    float rl[4];
    #pragma unroll
    for (int r = 0; r < 4; ++r) rl[r] = 1.0f / lrow[r];
    #pragma unroll
    for (int nb2 = 0; nb2 < 8; ++nb2) {
        const int col = h * DH + nb2 * 16 + (l & 15);
        #pragma unroll
        for (int r = 0; r < 4; ++r) {
            const int srow = s0 + w * 16 + (l >> 4) * 4 + r;
            out[((size_t)b * SS + srow) * CC + col] = f2bf(acc[nb2][r] * rl[r]);
        }
    }
}

// ---------------------------------------------------------------------------
extern "C" void kernel_launch(void* const* d_in, const int* in_sizes, int n_in,
                              void* d_out, int out_size, void* d_ws, size_t ws_size,
                              hipStream_t stream) {
    const float* x          = (const float*)d_in[0];
    const int*   seq_lens   = (const int*)d_in[1];
    const int*   grid_sizes = (const int*)d_in[2];
    const float* freqs      = (const float*)d_in[3];
    const float* Wq         = (const float*)d_in[4];
    const float* bq         = (const float*)d_in[5];
    const float* Wk         = (const float*)d_in[6];
    const float* bk         = (const float*)d_in[7];
    const float* Wv         = (const float*)d_in[8];
    const float* bv         = (const float*)d_in[9];
    const float* Wo         = (const float*)d_in[10];
    const float* bo         = (const float*)d_in[11];
    const float* nqw        = (const float*)d_in[12];
    const float* nkw        = (const float*)d_in[13];
    float* out = (float*)d_out;

    const size_t TE = (size_t)NTOK * CC;       // 9,437,184
    const size_t WE = (size_t)CC * CC;         // 2,359,296
    unsigned short* xb  = (unsigned short*)d_ws;
    unsigned short* wqb = xb + TE;
    unsigned short* wkb = wqb + WE;
    unsigned short* wvb = wkb + WE;
    unsigned short* wob = wvb + WE;
    unsigned short* qb  = wob + WE;
    unsigned short* kb  = qb + TE;
    unsigned short* vtb = kb + TE;
    unsigned short* ab  = vtb + TE;

    cast_bf16<<<dim3((int)(TE / 1024)), 256, 0, stream>>>(x, xb, (int)TE);
    cast_bf16<<<dim3((int)(WE / 1024)), 256, 0, stream>>>(Wq, wqb, (int)WE);
    cast_bf16<<<dim3((int)(WE / 1024)), 256, 0, stream>>>(Wk, wkb, (int)WE);
    cast_bf16<<<dim3((int)(WE / 1024)), 256, 0, stream>>>(Wv, wvb, (int)WE);
    cast_bf16<<<dim3((int)(WE / 1024)), 256, 0, stream>>>(Wo, wob, (int)WE);

    dim3 gg(NTOK / 128, CC / 128), gb(256);
    gemm_mfma<3><<<gg, gb, 0, stream>>>(xb, wqb, bq, qb);
    gemm_mfma<3><<<gg, gb, 0, stream>>>(xb, wkb, bk, kb);
    gemm_mfma<2><<<gg, gb, 0, stream>>>(xb, wvb, bv, vtb);

    norm_rope<<<dim3(NTOK), 256, 0, stream>>>(qb, nqw, freqs, grid_sizes, 0.08838834764831845f);
    norm_rope<<<dim3(NTOK), 256, 0, stream>>>(kb, nkw, freqs, grid_sizes, 1.0f);

    flash_attn_mfma<<<dim3(NB * NH * (SS / 64)), 256, 0, stream>>>(qb, kb, vtb, seq_lens, ab);

    gemm_mfma<0><<<gg, gb, 0, stream>>>(ab, wob, bo, out);
}

// Round 3
// 574.844 us; speedup vs baseline: 7.6376x; 1.1979x over previous
//
#include <hip/hip_runtime.h>
#include <math.h>

#define NB 2
#define SS 3072
#define CC 1536
#define NH 12
#define DH 128
#define NTOK (NB * SS)
#define WE (CC * CC)         // 2,359,296
#define LOG2E 1.4426950408889634f

typedef __attribute__((ext_vector_type(8))) short short8;
typedef __attribute__((ext_vector_type(4))) float floatx4;

#define GLOAD(g, l) __builtin_amdgcn_global_load_lds( \
    (const __attribute__((address_space(1))) void*)(g), \
    (__attribute__((address_space(3))) void*)(l), 16, 0, 0)

__device__ __forceinline__ unsigned short f2bf(float f) {
    unsigned u = __float_as_uint(f);
    u += 0x7fffu + ((u >> 16) & 1u);   // RNE
    return (unsigned short)(u >> 16);
}

// ---------------------------------------------------------------------------
// Cast x (4*WE) + Wq,Wk,Wv,Wo (WE each) to one contiguous bf16 region.
// grid (WE/1024, 8): y<4 -> quarter of x; y>=4 -> W[y-4].
// ---------------------------------------------------------------------------
__global__ __launch_bounds__(256) void cast_all(
    const float* __restrict__ x,
    const float* __restrict__ w0, const float* __restrict__ w1,
    const float* __restrict__ w2, const float* __restrict__ w3,
    unsigned short* __restrict__ o)
{
    const int y = blockIdx.y;
    const float* src = (y < 4) ? x + (size_t)y * WE
                     : (y == 4) ? w0 : (y == 5) ? w1 : (y == 6) ? w2 : w3;
    size_t i = ((size_t)blockIdx.x * 256 + threadIdx.x) * 4;
    float4 v = *(const float4*)&src[i];
    uint2 u;
    u.x = (unsigned)f2bf(v.x) | ((unsigned)f2bf(v.y) << 16);
    u.y = (unsigned)f2bf(v.z) | ((unsigned)f2bf(v.w) << 16);
    *(uint2*)&o[(size_t)y * WE + i] = u;
}

// ---------------------------------------------------------------------------
// Fused QKV GEMM: for jseg 0,1,2 computes X @ W{q,k,v}^T + b.
// jseg<2 -> bf16 (B,NH,S,DH); jseg==2 -> bf16 (B,NH,DH,S) (transposed V).
// 128x128 tile, BK=32, 4 waves. grid (48, 36).
// ---------------------------------------------------------------------------
__global__ __launch_bounds__(256) void qkv_gemm(
    const unsigned short* __restrict__ X,
    const unsigned short* __restrict__ Wqb, const unsigned short* __restrict__ Wkb,
    const unsigned short* __restrict__ Wvb,
    const float* __restrict__ bq, const float* __restrict__ bk,
    const float* __restrict__ bv,
    unsigned short* __restrict__ qo, unsigned short* __restrict__ ko,
    unsigned short* __restrict__ vto)
{
    __shared__ unsigned short As[128 * 32];
    __shared__ unsigned short Bs[128 * 32];
    const int tid = threadIdx.x;
    const int w = tid >> 6, l = tid & 63;
    const int jseg = blockIdx.y / 12;
    const unsigned short* Wt = (jseg == 0) ? Wqb : (jseg == 1) ? Wkb : Wvb;
    const float* bias        = (jseg == 0) ? bq  : (jseg == 1) ? bk  : bv;
    unsigned short* Y        = (jseg == 0) ? qo  : (jseg == 1) ? ko  : vto;
    const int i0 = blockIdx.x * 128, j0 = (blockIdx.y % 12) * 128;
    const int srow = tid >> 2;
    const int sk8 = (tid & 3) * 8;

    floatx4 acc[4][4] = {};
    for (int k0 = 0; k0 < CC; k0 += 32) {
        __syncthreads();
        GLOAD(X + (size_t)(i0 + srow) * CC + k0 + sk8,        As + (size_t)tid * 8);
        GLOAD(X + (size_t)(i0 + 64 + srow) * CC + k0 + sk8,   As + (size_t)(256 + tid) * 8);
        GLOAD(Wt + (size_t)(j0 + srow) * CC + k0 + sk8,       Bs + (size_t)tid * 8);
        GLOAD(Wt + (size_t)(j0 + 64 + srow) * CC + k0 + sk8,  Bs + (size_t)(256 + tid) * 8);
        __syncthreads();
        const int wr = (w >> 1) * 64, wc = (w & 1) * 64;
        short8 af[4], bf[4];
        #pragma unroll
        for (int mb = 0; mb < 4; ++mb)
            af[mb] = *(const short8*)&As[(wr + mb * 16 + (l & 15)) * 32 + (l >> 4) * 8];
        #pragma unroll
        for (int nb = 0; nb < 4; ++nb)
            bf[nb] = *(const short8*)&Bs[(wc + nb * 16 + (l & 15)) * 32 + (l >> 4) * 8];
        #pragma unroll
        for (int mb = 0; mb < 4; ++mb)
            #pragma unroll
            for (int nb = 0; nb < 4; ++nb)
                acc[mb][nb] = __builtin_amdgcn_mfma_f32_16x16x32_bf16(
                    af[mb], bf[nb], acc[mb][nb], 0, 0, 0);
    }

    const int wr = (w >> 1) * 64, wc = (w & 1) * 64;
    #pragma unroll
    for (int mb = 0; mb < 4; ++mb)
        #pragma unroll
        for (int nb = 0; nb < 4; ++nb) {
            const int n = j0 + wc + nb * 16 + (l & 15);
            const float bv2 = bias[n];
            const int h = n >> 7, td = n & 127;
            #pragma unroll
            for (int r = 0; r < 4; ++r) {
                const int m = i0 + wr + mb * 16 + (l >> 4) * 4 + r;
                const float val = acc[mb][nb][r] + bv2;
                const int b = (m >= SS) ? 1 : 0;
                const int s = m - b * SS;
                if (jseg < 2)
                    Y[((size_t)(b * NH + h) * SS + s) * DH + td] = f2bf(val);
                else
                    Y[((size_t)(b * NH + h) * DH + td) * SS + s] = f2bf(val);
            }
        }
}

// ---------------------------------------------------------------------------
// O-projection: fp32 out (B,S,C) = A @ Wo^T + bo.
// ---------------------------------------------------------------------------
__global__ __launch_bounds__(256) void gemm_o(
    const unsigned short* __restrict__ X, const unsigned short* __restrict__ Wt,
    const float* __restrict__ bias, float* __restrict__ Y)
{
    __shared__ unsigned short As[128 * 32];
    __shared__ unsigned short Bs[128 * 32];
    const int tid = threadIdx.x;
    const int w = tid >> 6, l = tid & 63;
    const int i0 = blockIdx.x * 128, j0 = blockIdx.y * 128;
    const int srow = tid >> 2;
    const int sk8 = (tid & 3) * 8;

    floatx4 acc[4][4] = {};
    for (int k0 = 0; k0 < CC; k0 += 32) {
        __syncthreads();
        GLOAD(X + (size_t)(i0 + srow) * CC + k0 + sk8,        As + (size_t)tid * 8);
        GLOAD(X + (size_t)(i0 + 64 + srow) * CC + k0 + sk8,   As + (size_t)(256 + tid) * 8);
        GLOAD(Wt + (size_t)(j0 + srow) * CC + k0 + sk8,       Bs + (size_t)tid * 8);
        GLOAD(Wt + (size_t)(j0 + 64 + srow) * CC + k0 + sk8,  Bs + (size_t)(256 + tid) * 8);
        __syncthreads();
        const int wr = (w >> 1) * 64, wc = (w & 1) * 64;
        short8 af[4], bf[4];
        #pragma unroll
        for (int mb = 0; mb < 4; ++mb)
            af[mb] = *(const short8*)&As[(wr + mb * 16 + (l & 15)) * 32 + (l >> 4) * 8];
        #pragma unroll
        for (int nb = 0; nb < 4; ++nb)
            bf[nb] = *(const short8*)&Bs[(wc + nb * 16 + (l & 15)) * 32 + (l >> 4) * 8];
        #pragma unroll
        for (int mb = 0; mb < 4; ++mb)
            #pragma unroll
            for (int nb = 0; nb < 4; ++nb)
                acc[mb][nb] = __builtin_amdgcn_mfma_f32_16x16x32_bf16(
                    af[mb], bf[nb], acc[mb][nb], 0, 0, 0);
    }

    const int wr = (w >> 1) * 64, wc = (w & 1) * 64;
    #pragma unroll
    for (int mb = 0; mb < 4; ++mb)
        #pragma unroll
        for (int nb = 0; nb < 4; ++nb) {
            const int n = j0 + wc + nb * 16 + (l & 15);
            const float bv = bias[n];
            #pragma unroll
            for (int r = 0; r < 4; ++r) {
                const int m = i0 + wr + mb * 16 + (l >> 4) * 4 + r;
                Y[(size_t)m * CC + n] = acc[mb][nb][r] + bv;
            }
        }
}

// ---------------------------------------------------------------------------
// Fused RMSNorm + RoPE, in-place bf16 (B,NH,S,DH). grid(2*NTOK):
// first half -> q (scale = 1/sqrt(d)*log2(e)), second half -> k.
// ---------------------------------------------------------------------------
__global__ __launch_bounds__(256) void norm_rope(
    unsigned short* __restrict__ qb, unsigned short* __restrict__ kb,
    const float* __restrict__ nqw, const float* __restrict__ nkw,
    const float* __restrict__ freqs, const int* __restrict__ gsz)
{
    const int bid = blockIdx.x;
    const int which = (bid >= NTOK) ? 1 : 0;
    const int tok = bid - which * NTOK;
    unsigned short* t       = which ? kb : qb;
    const float* wgt        = which ? nkw : nqw;
    const float outscale    = which ? 1.0f : 0.08838834764831845f * LOG2E;
    const int b = tok / SS, s = tok - b * SS;
    const int Hg = gsz[1], Wg = gsz[2];
    const int f = s / (Hg * Wg);
    const int rem = s - f * Hg * Wg;
    const int hh = rem / Wg;
    const int ww = rem - hh * Wg;
    const int tid = threadIdx.x;

    float2 vals[3];
    size_t addrs[3];
    float ss = 0.f;
    #pragma unroll
    for (int kt = 0; kt < 3; ++kt) {
        int p = tid + kt * 256;
        int h = p >> 6, pj = p & 63;
        size_t addr = ((size_t)(b * NH + h) * SS + s) * DH + 2 * pj;
        addrs[kt] = addr;
        unsigned u = *(const unsigned*)&t[addr];
        float2 v;
        v.x = __uint_as_float(u << 16);
        v.y = __uint_as_float(u & 0xffff0000u);
        vals[kt] = v;
        ss += v.x * v.x + v.y * v.y;
    }
    #pragma unroll
    for (int off = 32; off > 0; off >>= 1) ss += __shfl_down(ss, off, 64);
    __shared__ float red[4];
    if ((tid & 63) == 0) red[tid >> 6] = ss;
    __syncthreads();
    const float total = red[0] + red[1] + red[2] + red[3];
    const float rstd = rsqrtf(total * (1.0f / CC) + 1e-6f) * outscale;

    #pragma unroll
    for (int kt = 0; kt < 3; ++kt) {
        int p = tid + kt * 256;
        int h = p >> 6, pj = p & 63;
        int row = (pj < 22) ? f : ((pj < 43) ? hh : ww);
        float ang = freqs[row * 64 + pj];
        float sn, cs;
        sincosf(ang, &sn, &cs);
        int ch = h * DH + 2 * pj;
        float te = vals[kt].x * rstd * wgt[ch];
        float to = vals[kt].y * rstd * wgt[ch + 1];
        unsigned o = (unsigned)f2bf(te * cs - to * sn) |
                     ((unsigned)f2bf(te * sn + to * cs) << 16);
        *(unsigned*)&t[addrs[kt]] = o;
    }
}

// ---------------------------------------------------------------------------
// MFMA flash attention without max-subtraction (scores bounded; q pre-scaled
// by 1/sqrt(d)*log2e so p = exp2(s)). lsum kept per-lane, reduced once at end.
// Ps aliases Qs (Q LDS dead after fragment load) -> 48 KB LDS, 3 blocks/CU.
// ---------------------------------------------------------------------------
__global__ __launch_bounds__(256) void flash_attn_mfma(
    const unsigned short* __restrict__ qg, const unsigned short* __restrict__ kg,
    const unsigned short* __restrict__ vg, const int* __restrict__ seq_lens,
    unsigned short* __restrict__ out)
{
    __shared__ unsigned short Qs[4 * 64 * 32];   // reused as Ps after Q-frag load
    __shared__ unsigned short Ks[4 * 64 * 32];
    __shared__ unsigned short Vs[2 * 128 * 32];

    const int tid = threadIdx.x;
    const int w = tid >> 6, l = tid & 63;
    const int bid = blockIdx.x;
    const int qt  = bid / (NB * NH);          // balanced: (h,b) fastest
    const int rem0 = bid - qt * (NB * NH);
    const int h = rem0 >> 1;
    const int b = rem0 & 1;
    const int slen = seq_lens[b];
    const int s0 = qt * 64;

    const unsigned short* qbase = qg + ((size_t)(b * NH + h) * SS + s0) * DH;
    const unsigned short* kbase = kg + ((size_t)(b * NH + h) * SS) * DH;
    const unsigned short* vbase = vg + ((size_t)(b * NH + h) * DH) * SS;
    unsigned short* Psw = Qs + (size_t)w * (16 * 72);   // per-wave slab

    #pragma unroll
    for (int i = 0; i < 4; ++i) {
        int cid = i * 256 + tid;
        int kc = cid >> 8, r2 = cid & 255, row = r2 >> 2, k8 = (r2 & 3) * 8;
        GLOAD(qbase + row * DH + kc * 32 + k8, Qs + (size_t)cid * 8);
    }
    __syncthreads();
    short8 qf[4];
    #pragma unroll
    for (int kc = 0; kc < 4; ++kc)
        qf[kc] = *(const short8*)&Qs[kc * 2048 + (w * 16 + (l & 15)) * 32 + (l >> 4) * 8];

    floatx4 acc[8] = {};
    float lsum[4] = {};
    const int ntiles = (slen + 63) >> 6;

    for (int kt = 0; kt < ntiles; ++kt) {
        __syncthreads();
        #pragma unroll
        for (int i = 0; i < 4; ++i) {
            int cid = i * 256 + tid;
            int kc = cid >> 8, r2 = cid & 255, row = r2 >> 2, k8 = (r2 & 3) * 8;
            GLOAD(kbase + (size_t)(kt * 64 + row) * DH + kc * 32 + k8, Ks + (size_t)cid * 8);
        }
        #pragma unroll
        for (int i = 0; i < 4; ++i) {
            int cid = i * 256 + tid;
            int ks = cid >> 9, r2 = cid & 511, dc = r2 >> 2, k8 = (r2 & 3) * 8;
            GLOAD(vbase + (size_t)dc * SS + kt * 64 + ks * 32 + k8, Vs + (size_t)cid * 8);
        }
        __syncthreads();

        // S = Q K^T  (16 q-rows x 64 keys per wave), logits already *log2e
        floatx4 sv[4] = {};
        #pragma unroll
        for (int nb = 0; nb < 4; ++nb)
            #pragma unroll
            for (int kc = 0; kc < 4; ++kc) {
                short8 kf = *(const short8*)&Ks[kc * 2048 + (nb * 16 + (l & 15)) * 32 + (l >> 4) * 8];
                sv[nb] = __builtin_amdgcn_mfma_f32_16x16x32_bf16(qf[kc], kf, sv[nb], 0, 0, 0);
            }

        // p = exp2(s); only the (single) partial tile needs masking
        const int valid = slen - kt * 64;
        float pv[4][4];
        if (valid >= 64) {
            #pragma unroll
            for (int nb = 0; nb < 4; ++nb)
                #pragma unroll
                for (int r = 0; r < 4; ++r)
                    pv[nb][r] = exp2f(sv[nb][r]);
        } else {
            #pragma unroll
            for (int nb = 0; nb < 4; ++nb) {
                const int key = nb * 16 + (l & 15);
                #pragma unroll
                for (int r = 0; r < 4; ++r)
                    pv[nb][r] = (key < valid) ? exp2f(sv[nb][r]) : 0.0f;
            }
        }
        #pragma unroll
        for (int r = 0; r < 4; ++r)
            lsum[r] += pv[0][r] + pv[1][r] + pv[2][r] + pv[3][r];

        // P -> LDS (bf16, A-operand layout transform); per-wave slab, no barrier
        #pragma unroll
        for (int nb = 0; nb < 4; ++nb)
            #pragma unroll
            for (int r = 0; r < 4; ++r)
                Psw[((l >> 4) * 4 + r) * 72 + nb * 16 + (l & 15)] = f2bf(pv[nb][r]);

        short8 pa[2];
        #pragma unroll
        for (int ks = 0; ks < 2; ++ks)
            pa[ks] = *(const short8*)&Psw[(l & 15) * 72 + ks * 32 + (l >> 4) * 8];
        #pragma unroll
        for (int nb2 = 0; nb2 < 8; ++nb2)
            #pragma unroll
            for (int ks = 0; ks < 2; ++ks) {
                short8 vf = *(const short8*)&Vs[ks * 4096 + (nb2 * 16 + (l & 15)) * 32 + (l >> 4) * 8];
                acc[nb2] = __builtin_amdgcn_mfma_f32_16x16x32_bf16(pa[ks], vf, acc[nb2], 0, 0, 0);
            }
    }

    float rl[4];
    #pragma unroll
    for (int r = 0; r < 4; ++r) {
        float s = lsum[r];
        #pragma unroll
        for (int mm = 1; mm < 16; mm <<= 1) s += __shfl_xor(s, mm, 64);
        rl[r] = 1.0f / s;
    }
    #pragma unroll
    for (int nb2 = 0; nb2 < 8; ++nb2) {
        const int col = h * DH + nb2 * 16 + (l & 15);
        #pragma unroll
        for (int r = 0; r < 4; ++r) {
            const int srow = s0 + w * 16 + (l >> 4) * 4 + r;
            out[((size_t)b * SS + srow) * CC + col] = f2bf(acc[nb2][r] * rl[r]);
        }
    }
}

// ---------------------------------------------------------------------------
extern "C" void kernel_launch(void* const* d_in, const int* in_sizes, int n_in,
                              void* d_out, int out_size, void* d_ws, size_t ws_size,
                              hipStream_t stream) {
    const float* x          = (const float*)d_in[0];
    const int*   seq_lens   = (const int*)d_in[1];
    const int*   grid_sizes = (const int*)d_in[2];
    const float* freqs      = (const float*)d_in[3];
    const float* Wq         = (const float*)d_in[4];
    const float* bq         = (const float*)d_in[5];
    const float* Wk         = (const float*)d_in[6];
    const float* bk         = (const float*)d_in[7];
    const float* Wv         = (const float*)d_in[8];
    const float* bv         = (const float*)d_in[9];
    const float* Wo         = (const float*)d_in[10];
    const float* bo         = (const float*)d_in[11];
    const float* nqw        = (const float*)d_in[12];
    const float* nkw        = (const float*)d_in[13];
    float* out = (float*)d_out;

    const size_t TE = (size_t)NTOK * CC;   // 9,437,184 (= 4*WE)
    unsigned short* xb  = (unsigned short*)d_ws;   // xb .. wob contiguous
    unsigned short* wqb = xb + TE;
    unsigned short* wkb = wqb + WE;
    unsigned short* wvb = wkb + WE;
    unsigned short* wob = wvb + WE;
    unsigned short* qb  = wob + WE;
    unsigned short* kb  = qb + TE;
    unsigned short* vtb = kb + TE;
    unsigned short* ab  = vtb + TE;

    cast_all<<<dim3(WE / 1024, 8), 256, 0, stream>>>(x, Wq, Wk, Wv, Wo, xb);

    qkv_gemm<<<dim3(NTOK / 128, 36), 256, 0, stream>>>(
        xb, wqb, wkb, wvb, bq, bk, bv, qb, kb, vtb);

    norm_rope<<<dim3(2 * NTOK), 256, 0, stream>>>(qb, kb, nqw, nkw, freqs, grid_sizes);

    flash_attn_mfma<<<dim3(NB * NH * (SS / 64)), 256, 0, stream>>>(qb, kb, vtb, seq_lens, ab);

    gemm_o<<<dim3(NTOK / 128, CC / 128), 256, 0, stream>>>(ab, wob, bo, out);
}

// Round 4
// 560.016 us; speedup vs baseline: 7.8399x; 1.0265x over previous
//
#include <hip/hip_runtime.h>
#include <math.h>

#define NB 2
#define SS 3072
#define CC 1536
#define NH 12
#define DH 128
#define NTOK (NB * SS)
#define WE (CC * CC)         // 2,359,296
#define LOG2E 1.4426950408889634f

typedef __attribute__((ext_vector_type(8))) short short8;
typedef __attribute__((ext_vector_type(4))) float floatx4;

#define GLOAD(g, l) __builtin_amdgcn_global_load_lds( \
    (const __attribute__((address_space(1))) void*)(g), \
    (__attribute__((address_space(3))) void*)(l), 16, 0, 0)

__device__ __forceinline__ unsigned short f2bf(float f) {
    unsigned u = __float_as_uint(f);
    u += 0x7fffu + ((u >> 16) & 1u);   // RNE
    return (unsigned short)(u >> 16);
}
// XOR-swizzled chunk index in a [rows][4-chunk] LDS slab (16B chunks).
// Breaks the 4-way quarter-wave phase conflict of row-stride-64B b128 reads:
// rows r and r+8 alias (2-way, free), all else distinct.
__device__ __forceinline__ int swz(int row, int q) {
    return row * 4 + (q ^ ((row >> 1) & 3));
}

// ---------------------------------------------------------------------------
// Cast x (4*WE) + Wq,Wk,Wv,Wo (WE each) to one contiguous bf16 region.
// ---------------------------------------------------------------------------
__global__ __launch_bounds__(256) void cast_all(
    const float* __restrict__ x,
    const float* __restrict__ w0, const float* __restrict__ w1,
    const float* __restrict__ w2, const float* __restrict__ w3,
    unsigned short* __restrict__ o)
{
    const int y = blockIdx.y;
    const float* src = (y < 4) ? x + (size_t)y * WE
                     : (y == 4) ? w0 : (y == 5) ? w1 : (y == 6) ? w2 : w3;
    size_t i = ((size_t)blockIdx.x * 256 + threadIdx.x) * 4;
    float4 v = *(const float4*)&src[i];
    uint2 u;
    u.x = (unsigned)f2bf(v.x) | ((unsigned)f2bf(v.y) << 16);
    u.y = (unsigned)f2bf(v.z) | ((unsigned)f2bf(v.w) << 16);
    *(uint2*)&o[(size_t)y * WE + i] = u;
}

// ---------------------------------------------------------------------------
// RoPE angle table: tab[s*64+pj] = (cos, sin). 768 blocks x 256.
// ---------------------------------------------------------------------------
__global__ __launch_bounds__(256) void rope_table(
    const float* __restrict__ freqs, const int* __restrict__ gsz,
    float2* __restrict__ tab)
{
    const int id = blockIdx.x * 256 + threadIdx.x;   // 0..196607
    const int s = id >> 6, pj = id & 63;
    const int Hg = gsz[1], Wg = gsz[2];
    const int f = s / (Hg * Wg);
    const int rem = s - f * Hg * Wg;
    const int hh = rem / Wg;
    const int ww = rem - hh * Wg;
    const int row = (pj < 22) ? f : ((pj < 43) ? hh : ww);
    float sn, cs;
    sincosf(freqs[row * 64 + pj], &sn, &cs);
    tab[id] = make_float2(cs, sn);
}

// ---------------------------------------------------------------------------
// Fused QKV GEMM (swizzled LDS). jseg 0,1 -> bf16 (B,NH,S,DH); 2 -> (B,NH,DH,S).
// ---------------------------------------------------------------------------
__global__ __launch_bounds__(256) void qkv_gemm(
    const unsigned short* __restrict__ X,
    const unsigned short* __restrict__ Wqb, const unsigned short* __restrict__ Wkb,
    const unsigned short* __restrict__ Wvb,
    const float* __restrict__ bq, const float* __restrict__ bk,
    const float* __restrict__ bv,
    unsigned short* __restrict__ qo, unsigned short* __restrict__ ko,
    unsigned short* __restrict__ vto)
{
    __shared__ unsigned short As[128 * 32];
    __shared__ unsigned short Bs[128 * 32];
    const int tid = threadIdx.x;
    const int w = tid >> 6, l = tid & 63;
    const int jseg = blockIdx.y / 12;
    const unsigned short* Wt = (jseg == 0) ? Wqb : (jseg == 1) ? Wkb : Wvb;
    const float* bias        = (jseg == 0) ? bq  : (jseg == 1) ? bk  : bv;
    unsigned short* Y        = (jseg == 0) ? qo  : (jseg == 1) ? ko  : vto;
    const int i0 = blockIdx.x * 128, j0 = (blockIdx.y % 12) * 128;
    const int srow = tid >> 2;
    const int gk8 = (((tid & 3) ^ ((srow >> 1) & 3))) * 8;   // swizzled global chunk

    floatx4 acc[4][4] = {};
    for (int k0 = 0; k0 < CC; k0 += 32) {
        __syncthreads();
        GLOAD(X + (size_t)(i0 + srow) * CC + k0 + gk8,        As + (size_t)tid * 8);
        GLOAD(X + (size_t)(i0 + 64 + srow) * CC + k0 + gk8,   As + (size_t)(256 + tid) * 8);
        GLOAD(Wt + (size_t)(j0 + srow) * CC + k0 + gk8,       Bs + (size_t)tid * 8);
        GLOAD(Wt + (size_t)(j0 + 64 + srow) * CC + k0 + gk8,  Bs + (size_t)(256 + tid) * 8);
        __syncthreads();
        const int wr = (w >> 1) * 64, wc = (w & 1) * 64;
        short8 af[4], bf[4];
        #pragma unroll
        for (int mb = 0; mb < 4; ++mb)
            af[mb] = *(const short8*)&As[swz(wr + mb * 16 + (l & 15), l >> 4) * 8];
        #pragma unroll
        for (int nb = 0; nb < 4; ++nb)
            bf[nb] = *(const short8*)&Bs[swz(wc + nb * 16 + (l & 15), l >> 4) * 8];
        #pragma unroll
        for (int mb = 0; mb < 4; ++mb)
            #pragma unroll
            for (int nb = 0; nb < 4; ++nb)
                acc[mb][nb] = __builtin_amdgcn_mfma_f32_16x16x32_bf16(
                    af[mb], bf[nb], acc[mb][nb], 0, 0, 0);
    }

    const int wr = (w >> 1) * 64, wc = (w & 1) * 64;
    #pragma unroll
    for (int mb = 0; mb < 4; ++mb)
        #pragma unroll
        for (int nb = 0; nb < 4; ++nb) {
            const int n = j0 + wc + nb * 16 + (l & 15);
            const float bv2 = bias[n];
            const int h = n >> 7, td = n & 127;
            #pragma unroll
            for (int r = 0; r < 4; ++r) {
                const int m = i0 + wr + mb * 16 + (l >> 4) * 4 + r;
                const float val = acc[mb][nb][r] + bv2;
                const int b = (m >= SS) ? 1 : 0;
                const int s = m - b * SS;
                if (jseg < 2)
                    Y[((size_t)(b * NH + h) * SS + s) * DH + td] = f2bf(val);
                else
                    Y[((size_t)(b * NH + h) * DH + td) * SS + s] = f2bf(val);
            }
        }
}

// ---------------------------------------------------------------------------
// O-projection (swizzled LDS): fp32 out (B,S,C) = A @ Wo^T + bo.
// ---------------------------------------------------------------------------
__global__ __launch_bounds__(256) void gemm_o(
    const unsigned short* __restrict__ X, const unsigned short* __restrict__ Wt,
    const float* __restrict__ bias, float* __restrict__ Y)
{
    __shared__ unsigned short As[128 * 32];
    __shared__ unsigned short Bs[128 * 32];
    const int tid = threadIdx.x;
    const int w = tid >> 6, l = tid & 63;
    const int i0 = blockIdx.x * 128, j0 = blockIdx.y * 128;
    const int srow = tid >> 2;
    const int gk8 = (((tid & 3) ^ ((srow >> 1) & 3))) * 8;

    floatx4 acc[4][4] = {};
    for (int k0 = 0; k0 < CC; k0 += 32) {
        __syncthreads();
        GLOAD(X + (size_t)(i0 + srow) * CC + k0 + gk8,        As + (size_t)tid * 8);
        GLOAD(X + (size_t)(i0 + 64 + srow) * CC + k0 + gk8,   As + (size_t)(256 + tid) * 8);
        GLOAD(Wt + (size_t)(j0 + srow) * CC + k0 + gk8,       Bs + (size_t)tid * 8);
        GLOAD(Wt + (size_t)(j0 + 64 + srow) * CC + k0 + gk8,  Bs + (size_t)(256 + tid) * 8);
        __syncthreads();
        const int wr = (w >> 1) * 64, wc = (w & 1) * 64;
        short8 af[4], bf[4];
        #pragma unroll
        for (int mb = 0; mb < 4; ++mb)
            af[mb] = *(const short8*)&As[swz(wr + mb * 16 + (l & 15), l >> 4) * 8];
        #pragma unroll
        for (int nb = 0; nb < 4; ++nb)
            bf[nb] = *(const short8*)&Bs[swz(wc + nb * 16 + (l & 15), l >> 4) * 8];
        #pragma unroll
        for (int mb = 0; mb < 4; ++mb)
            #pragma unroll
            for (int nb = 0; nb < 4; ++nb)
                acc[mb][nb] = __builtin_amdgcn_mfma_f32_16x16x32_bf16(
                    af[mb], bf[nb], acc[mb][nb], 0, 0, 0);
    }

    const int wr = (w >> 1) * 64, wc = (w & 1) * 64;
    #pragma unroll
    for (int mb = 0; mb < 4; ++mb)
        #pragma unroll
        for (int nb = 0; nb < 4; ++nb) {
            const int n = j0 + wc + nb * 16 + (l & 15);
            const float bv = bias[n];
            #pragma unroll
            for (int r = 0; r < 4; ++r) {
                const int m = i0 + wr + mb * 16 + (l >> 4) * 4 + r;
                Y[(size_t)m * CC + n] = acc[mb][nb][r] + bv;
            }
        }
}

// ---------------------------------------------------------------------------
// Fused RMSNorm + RoPE (table-driven), in-place bf16 (B,NH,S,DH).
// grid(2*NTOK): first half q (scale folds 1/sqrt(d)*log2e), second half k.
// ---------------------------------------------------------------------------
__global__ __launch_bounds__(256) void norm_rope(
    unsigned short* __restrict__ qb, unsigned short* __restrict__ kb,
    const float* __restrict__ nqw, const float* __restrict__ nkw,
    const float2* __restrict__ tab)
{
    const int bid = blockIdx.x;
    const int which = (bid >= NTOK) ? 1 : 0;
    const int tok = bid - which * NTOK;
    unsigned short* t    = which ? kb : qb;
    const float* wgt     = which ? nkw : nqw;
    const float outscale = which ? 1.0f : 0.08838834764831845f * LOG2E;
    const int b = tok / SS, s = tok - b * SS;
    const int tid = threadIdx.x;

    float2 vals[3];
    size_t addrs[3];
    float ss = 0.f;
    #pragma unroll
    for (int kt = 0; kt < 3; ++kt) {
        int p = tid + kt * 256;
        int h = p >> 6, pj = p & 63;
        size_t addr = ((size_t)(b * NH + h) * SS + s) * DH + 2 * pj;
        addrs[kt] = addr;
        unsigned u = *(const unsigned*)&t[addr];
        float2 v;
        v.x = __uint_as_float(u << 16);
        v.y = __uint_as_float(u & 0xffff0000u);
        vals[kt] = v;
        ss += v.x * v.x + v.y * v.y;
    }
    #pragma unroll
    for (int off = 32; off > 0; off >>= 1) ss += __shfl_down(ss, off, 64);
    __shared__ float red[4];
    if ((tid & 63) == 0) red[tid >> 6] = ss;
    __syncthreads();
    const float total = red[0] + red[1] + red[2] + red[3];
    const float rstd = rsqrtf(total * (1.0f / CC) + 1e-6f) * outscale;

    #pragma unroll
    for (int kt = 0; kt < 3; ++kt) {
        int p = tid + kt * 256;
        int h = p >> 6, pj = p & 63;
        float2 cssn = tab[s * 64 + pj];
        int ch = h * DH + 2 * pj;
        float te = vals[kt].x * rstd * wgt[ch];
        float to = vals[kt].y * rstd * wgt[ch + 1];
        unsigned o = (unsigned)f2bf(te * cssn.x - to * cssn.y) |
                     ((unsigned)f2bf(te * cssn.y + to * cssn.x) << 16);
        *(unsigned*)&t[addrs[kt]] = o;
    }
}

// ---------------------------------------------------------------------------
// MFMA flash attention, 128-row Q tile, 2x register blocking, swizzled LDS.
// Wave w owns q-rows [32w, 32w+32): Q frags in registers; K/V frag reads
// shared across the 2 row-blocks. No max-subtraction (bounded logits,
// q pre-scaled by 1/sqrt(d)*log2e). P per-wave slab aliases Qs.
// ---------------------------------------------------------------------------
__global__ __launch_bounds__(256, 2) void flash_attn_mfma(
    const unsigned short* __restrict__ qg, const unsigned short* __restrict__ kg,
    const unsigned short* __restrict__ vg, const int* __restrict__ seq_lens,
    unsigned short* __restrict__ out)
{
    __shared__ unsigned short Qs[128 * 128];     // 32 KB; P slabs alias after qf load
    __shared__ unsigned short Ks[64 * 128];      // 16 KB  [kc][key][32] swizzled
    __shared__ unsigned short Vs[128 * 64];      // 16 KB  [ks][dcol][32] swizzled

    const int tid = threadIdx.x;
    const int w = tid >> 6, l = tid & 63;
    const int bid = blockIdx.x;
    const int qt = bid / (NB * NH);
    const int rem0 = bid - qt * (NB * NH);
    const int h = rem0 >> 1;
    const int b = rem0 & 1;
    const int slen = seq_lens[b];
    const int s0 = qt * 128;

    const unsigned short* qbase = qg + ((size_t)(b * NH + h) * SS + s0) * DH;
    const unsigned short* kbase = kg + ((size_t)(b * NH + h) * SS) * DH;
    const unsigned short* vbase = vg + ((size_t)(b * NH + h) * DH) * SS;
    unsigned short* Psw = Qs + (size_t)w * (32 * 72);   // per-wave P slab (4.5 KB)

    // stage Q: 2048 16B chunks, swizzled within each [128-row][4-chunk] kc-slab
    #pragma unroll
    for (int i = 0; i < 8; ++i) {
        int cid = i * 256 + tid;
        int kc = cid >> 9, r2 = cid & 511, row = r2 >> 2, sq = r2 & 3;
        GLOAD(qbase + (size_t)row * DH + kc * 32 + (sq ^ ((row >> 1) & 3)) * 8,
              Qs + (size_t)cid * 8);
    }
    __syncthreads();
    short8 qf[2][4];
    #pragma unroll
    for (int rb = 0; rb < 2; ++rb)
        #pragma unroll
        for (int kc = 0; kc < 4; ++kc)
            qf[rb][kc] = *(const short8*)&Qs[(kc * 512 + swz(w * 32 + rb * 16 + (l & 15), l >> 4)) * 8];

    floatx4 acc[2][8] = {};
    float lsum[2][4] = {};
    const int ntiles = (slen + 63) >> 6;

    for (int kt = 0; kt < ntiles; ++kt) {
        __syncthreads();
        #pragma unroll
        for (int i = 0; i < 4; ++i) {
            int cid = i * 256 + tid;
            int kc = cid >> 8, r2 = cid & 255, row = r2 >> 2, sq = r2 & 3;
            GLOAD(kbase + (size_t)(kt * 64 + row) * DH + kc * 32 + (sq ^ ((row >> 1) & 3)) * 8,
                  Ks + (size_t)cid * 8);
        }
        #pragma unroll
        for (int i = 0; i < 4; ++i) {
            int cid = i * 256 + tid;
            int ks = cid >> 9, r2 = cid & 511, dc = r2 >> 2, sq = r2 & 3;
            GLOAD(vbase + (size_t)dc * SS + kt * 64 + ks * 32 + (sq ^ ((dc >> 1) & 3)) * 8,
                  Vs + (size_t)cid * 8);
        }
        __syncthreads();

        // S = Q K^T : per wave 32 q-rows x 64 keys; K frags shared across rb
        floatx4 sv[2][4] = {};
        #pragma unroll
        for (int kc = 0; kc < 4; ++kc) {
            short8 kf[4];
            #pragma unroll
            for (int nb = 0; nb < 4; ++nb)
                kf[nb] = *(const short8*)&Ks[(kc * 256 + swz(nb * 16 + (l & 15), l >> 4)) * 8];
            #pragma unroll
            for (int rb = 0; rb < 2; ++rb)
                #pragma unroll
                for (int nb = 0; nb < 4; ++nb)
                    sv[rb][nb] = __builtin_amdgcn_mfma_f32_16x16x32_bf16(
                        qf[rb][kc], kf[nb], sv[rb][nb], 0, 0, 0);
        }

        // p = exp2(s); mask only the single partial tile
        const int valid = slen - kt * 64;
        #pragma unroll
        for (int rb = 0; rb < 2; ++rb) {
            if (valid >= 64) {
                #pragma unroll
                for (int nb = 0; nb < 4; ++nb)
                    #pragma unroll
                    for (int r = 0; r < 4; ++r)
                        sv[rb][nb][r] = exp2f(sv[rb][nb][r]);
            } else {
                #pragma unroll
                for (int nb = 0; nb < 4; ++nb) {
                    const int key = nb * 16 + (l & 15);
                    #pragma unroll
                    for (int r = 0; r < 4; ++r)
                        sv[rb][nb][r] = (key < valid) ? exp2f(sv[rb][nb][r]) : 0.0f;
                }
            }
            #pragma unroll
            for (int r = 0; r < 4; ++r)
                lsum[rb][r] += sv[rb][0][r] + sv[rb][1][r] + sv[rb][2][r] + sv[rb][3][r];
            #pragma unroll
            for (int nb = 0; nb < 4; ++nb)
                #pragma unroll
                for (int r = 0; r < 4; ++r)
                    Psw[(rb * 16 + (l >> 4) * 4 + r) * 72 + nb * 16 + (l & 15)] =
                        f2bf(sv[rb][nb][r]);
        }

        // O += P V : V frags shared across rb
        #pragma unroll
        for (int ks = 0; ks < 2; ++ks) {
            short8 pa[2];
            #pragma unroll
            for (int rb = 0; rb < 2; ++rb)
                pa[rb] = *(const short8*)&Psw[(rb * 16 + (l & 15)) * 72 + ks * 32 + (l >> 4) * 8];
            #pragma unroll
            for (int nb2 = 0; nb2 < 8; ++nb2) {
                short8 vf = *(const short8*)&Vs[(ks * 512 + swz(nb2 * 16 + (l & 15), l >> 4)) * 8];
                #pragma unroll
                for (int rb = 0; rb < 2; ++rb)
                    acc[rb][nb2] = __builtin_amdgcn_mfma_f32_16x16x32_bf16(
                        pa[rb], vf, acc[rb][nb2], 0, 0, 0);
            }
        }
    }

    #pragma unroll
    for (int rb = 0; rb < 2; ++rb) {
        float rl[4];
        #pragma unroll
        for (int r = 0; r < 4; ++r) {
            float s = lsum[rb][r];
            #pragma unroll
            for (int mm = 1; mm < 16; mm <<= 1) s += __shfl_xor(s, mm, 64);
            rl[r] = 1.0f / s;
        }
        #pragma unroll
        for (int nb2 = 0; nb2 < 8; ++nb2) {
            const int col = h * DH + nb2 * 16 + (l & 15);
            #pragma unroll
            for (int r = 0; r < 4; ++r) {
                const int srow = s0 + w * 32 + rb * 16 + (l >> 4) * 4 + r;
                out[((size_t)b * SS + srow) * CC + col] = f2bf(acc[rb][nb2][r] * rl[r]);
            }
        }
    }
}

// ---------------------------------------------------------------------------
extern "C" void kernel_launch(void* const* d_in, const int* in_sizes, int n_in,
                              void* d_out, int out_size, void* d_ws, size_t ws_size,
                              hipStream_t stream) {
    const float* x          = (const float*)d_in[0];
    const int*   seq_lens   = (const int*)d_in[1];
    const int*   grid_sizes = (const int*)d_in[2];
    const float* freqs      = (const float*)d_in[3];
    const float* Wq         = (const float*)d_in[4];
    const float* bq         = (const float*)d_in[5];
    const float* Wk         = (const float*)d_in[6];
    const float* bk         = (const float*)d_in[7];
    const float* Wv         = (const float*)d_in[8];
    const float* bv         = (const float*)d_in[9];
    const float* Wo         = (const float*)d_in[10];
    const float* bo         = (const float*)d_in[11];
    const float* nqw        = (const float*)d_in[12];
    const float* nkw        = (const float*)d_in[13];
    float* out = (float*)d_out;

    const size_t TE = (size_t)NTOK * CC;   // 9,437,184 (= 4*WE)
    unsigned short* xb  = (unsigned short*)d_ws;   // xb..wob contiguous
    unsigned short* wqb = xb + TE;
    unsigned short* wkb = wqb + WE;
    unsigned short* wvb = wkb + WE;
    unsigned short* wob = wvb + WE;
    unsigned short* qb  = wob + WE;
    unsigned short* kb  = qb + TE;
    unsigned short* vtb = kb + TE;
    unsigned short* ab  = vtb + TE;
    float2* tab = (float2*)(ab + TE);      // 3072*64 float2 = 1.5 MB

    cast_all<<<dim3(WE / 1024, 8), 256, 0, stream>>>(x, Wq, Wk, Wv, Wo, xb);
    rope_table<<<dim3(SS * 64 / 256), 256, 0, stream>>>(freqs, grid_sizes, tab);

    qkv_gemm<<<dim3(NTOK / 128, 36), 256, 0, stream>>>(
        xb, wqb, wkb, wvb, bq, bk, bv, qb, kb, vtb);

    norm_rope<<<dim3(2 * NTOK), 256, 0, stream>>>(qb, kb, nqw, nkw, tab);

    flash_attn_mfma<<<dim3(NB * NH * (SS / 128)), 256, 0, stream>>>(qb, kb, vtb, seq_lens, ab);

    gemm_o<<<dim3(NTOK / 128, CC / 128), 256, 0, stream>>>(ab, wob, bo, out);
}